// Round 3
// baseline (213.618 us; speedup 1.0000x reference)
//
#include <hip/hip_runtime.h>

#define BATCH   65536
#define STEPS   200
#define SEG     8
#define NSEG    (STEPS / SEG)    // 25
#define NCKPT   (NSEG - 1)       // 24 checkpoints (state after steps 8,16,...,192)
#define LSTRIDE 33               // 8 float4 = 32 dwords + 1 pad dword

__device__ __forceinline__ float4 seir_step(float4 x, float A, float Binv, float C) {
    float infl = Binv * x.x * (x.y + x.z);   // Binv = B/N_POP
    float ae = A * x.y;
    float ci = C * x.z;
    float d0 = -infl;
    float d1 = infl - ae;
    float d2 = ae - ci;
    float d3 = ci;
    d0 = fminf(fmaxf(d0, -100000.0f), 100000.0f);
    d1 = fminf(fmaxf(d1, -100000.0f), 100000.0f);
    d2 = fminf(fmaxf(d2, -100000.0f), 100000.0f);
    d3 = fminf(fmaxf(d3, -100000.0f), 100000.0f);
    x.x += 0.5f * d0;
    x.y += 0.5f * d1;
    x.z += 0.5f * d2;
    x.w += 0.5f * d3;
    return x;
}

// Phase 1: full chain, write only checkpoints (coalesced: index k*BATCH+b).
__global__ __launch_bounds__(256) void seir_phase1(
    const float* __restrict__ init,
    const float* __restrict__ w,
    float4* __restrict__ cp)
{
    const int b = blockIdx.x * 256 + threadIdx.x;
    const float A = w[4], Binv = w[5] * (1.0f / 100000.0f), C = w[6];

    float4 x = reinterpret_cast<const float4*>(init)[b];
    for (int k = 0; k < NCKPT; ++k) {
        #pragma unroll
        for (int t = 0; t < SEG; ++t) x = seir_step(x, A, Binv, C);
        cp[(size_t)k * BATCH + b] = x;   // full-line coalesced store
    }
}

// Phase 2: one 8-step segment per thread, 25x parallelism; LDS transpose,
// full-line coalesced flush. One block = one segment x 256 batch elems.
__global__ __launch_bounds__(256) void seir_phase2(
    const float* __restrict__ init,
    const float* __restrict__ w,
    const float4* __restrict__ cp,
    float4* __restrict__ out4)
{
    __shared__ float lds[256 * LSTRIDE];   // 33.8 KB -> 4 blocks/CU

    const int tid  = threadIdx.x;
    const int lane = tid & 63;
    const int wv   = tid >> 6;
    const int seg  = blockIdx.x >> 8;              // 0..24
    const int bblk = (blockIdx.x & 255) * 256;     // block's batch base
    const int b    = bblk + tid;

    const float A = w[4], Binv = w[5] * (1.0f / 100000.0f), C = w[6];

    float4 x = (seg == 0) ? reinterpret_cast<const float4*>(init)[b]
                          : cp[(size_t)(seg - 1) * BATCH + b];

    float* wlds = lds + wv * 64 * LSTRIDE;

    // banks: (lane + 4*tt + c) % 32 -> 2-way max: free
    #pragma unroll
    for (int t = 0; t < SEG; ++t) {
        x = seir_step(x, A, Binv, C);
        const int a = lane * LSTRIDE + t * 4;
        wlds[a + 0] = x.x;
        wlds[a + 1] = x.y;
        wlds[a + 2] = x.z;
        wlds[a + 3] = x.w;
    }
    __syncthreads();   // single barrier per kernel; vmcnt already drained (loads only)

    // Flush: lane group of 8 covers one batch elem's 8 consecutive float4
    // (128 B contiguous) -> each store instr writes 16 FULL 64B lines.
    const int wb = bblk + wv * 64;   // wave's batch base
    const int t0 = seg * SEG;
    #pragma unroll
    for (int k = 0; k < 8; ++k) {
        const int s  = k * 64 + lane;
        const int bb = s >> 3;
        const int j  = s & 7;
        const int a  = bb * LSTRIDE + j * 4;
        float4 v = make_float4(wlds[a + 0], wlds[a + 1], wlds[a + 2], wlds[a + 3]);
        out4[(size_t)(wb + bb) * STEPS + t0 + j] = v;
    }
}

// Fallback (round-2 monolithic) in case ws is too small for checkpoints.
__global__ __launch_bounds__(64) void seir_mono(
    const float* __restrict__ init,
    const float* __restrict__ w,
    float4* __restrict__ out4)
{
    __shared__ float lds[64 * LSTRIDE];
    const int lane   = threadIdx.x;
    const int base_b = blockIdx.x * 64;
    const float A = w[4], Binv = w[5] * (1.0f / 100000.0f), C = w[6];
    float4 x = reinterpret_cast<const float4*>(init)[base_b + lane];
    for (int chunk = 0; chunk < NSEG; ++chunk) {
        #pragma unroll
        for (int tt = 0; tt < SEG; ++tt) {
            x = seir_step(x, A, Binv, C);
            const int a = lane * LSTRIDE + tt * 4;
            lds[a] = x.x; lds[a + 1] = x.y; lds[a + 2] = x.z; lds[a + 3] = x.w;
        }
        __syncthreads();
        const int t0 = chunk * SEG;
        #pragma unroll
        for (int k = 0; k < 8; ++k) {
            const int s = k * 64 + lane;
            const int bb = s >> 3, j = s & 7, a = bb * LSTRIDE + j * 4;
            float4 v = make_float4(lds[a], lds[a + 1], lds[a + 2], lds[a + 3]);
            out4[(size_t)(base_b + bb) * STEPS + t0 + j] = v;
        }
        __syncthreads();
    }
}

extern "C" void kernel_launch(void* const* d_in, const int* in_sizes, int n_in,
                              void* d_out, int out_size, void* d_ws, size_t ws_size,
                              hipStream_t stream) {
    const float* init = (const float*)d_in[0];
    const float* w    = (const float*)d_in[1];
    float4* out4      = (float4*)d_out;

    const size_t cp_bytes = (size_t)NCKPT * BATCH * sizeof(float4);  // 25.2 MB
    if (ws_size >= cp_bytes) {
        float4* cp = (float4*)d_ws;
        seir_phase1<<<dim3(BATCH / 256), dim3(256), 0, stream>>>(init, w, cp);
        seir_phase2<<<dim3((BATCH / 256) * NSEG), dim3(256), 0, stream>>>(init, w, cp, out4);
    } else {
        seir_mono<<<dim3(BATCH / 64), dim3(64), 0, stream>>>(init, w, out4);
    }
}